// Round 14
// baseline (208.574 us; speedup 1.0000x reference)
//
#include <hip/hip_runtime.h>

typedef short short8 __attribute__((ext_vector_type(8)));
typedef short short4_ __attribute__((ext_vector_type(4)));
typedef float f32x4 __attribute__((ext_vector_type(4)));

#define GLD16(gsrc, ldst) \
  __builtin_amdgcn_global_load_lds((__attribute__((address_space(1))) const void*)(gsrc), \
                                   (__attribute__((address_space(3))) void*)(ldst), 16, 0, 0)

// Raw barrier: wait only for LDS ops (dbuf handoff); global stores stay in flight.
#define BAR() do { asm volatile("s_waitcnt lgkmcnt(0)" ::: "memory"); \
  __builtin_amdgcn_sched_barrier(0); __builtin_amdgcn_s_barrier(); } while (0)

static __device__ __forceinline__ short f2bf(float f) {
  union { float f; unsigned u; } x; x.f = f;
  unsigned r = x.u + 0x7fffu + ((x.u >> 16) & 1u);
  return (short)(r >> 16);
}
static __device__ __forceinline__ float bf2f(unsigned short h) {
  union { unsigned u; float f; } x; x.u = ((unsigned)h) << 16;
  return x.f;
}

// ---------------- kernel 1: cast q,k,v f32 -> bf16 ----------------
__global__ __launch_bounds__(256) void cast_qkv(
    const float* __restrict__ q, const float* __restrict__ k, const float* __restrict__ v,
    short* __restrict__ xq, short* __restrict__ xk, short* __restrict__ xv) {
  int z = blockIdx.z;
  const float* s = (z == 0) ? q : (z == 1) ? k : v;
  short* d = (z == 0) ? xq : (z == 1) ? xk : xv;
  int i = (blockIdx.x * 256 + threadIdx.x) * 4;
  float4 f = *(const float4*)(s + i);
  short4_ o;
  o[0] = f2bf(f.x); o[1] = f2bf(f.y); o[2] = f2bf(f.z); o[3] = f2bf(f.w);
  *(short4_*)(d + i) = o;
}

// ------------- kernel 2: pack W (H,D,DK) f32 -> Bt (H*DK, D) bf16 -------------
__global__ __launch_bounds__(256) void pack_w(
    const float* __restrict__ wq, const float* __restrict__ wk, const float* __restrict__ wv,
    short* __restrict__ oq, short* __restrict__ ok, short* __restrict__ ov) {
  int z = blockIdx.z;
  const float* W = (z == 0) ? wq : (z == 1) ? wk : wv;
  short* o = ((z == 0) ? oq : (z == 1) ? ok : ov) + (size_t)blockIdx.x * 1024;
  int c = blockIdx.x;
  int h = c >> 6, kk = c & 63;
  const float* src = W + (size_t)h * 65536 + kk;  // + d*64
  #pragma unroll
  for (int it = 0; it < 4; ++it) {
    int d = it * 256 + threadIdx.x;
    o[d] = f2bf(src[(size_t)d * 64]);
  }
}

// ------------- kernel 3: projection GEMM (GLD16 staging, validated) -------------
// z=0 -> pq rows, z=1 -> pk rows, z=2 -> vt DIRECT (transposed epilogue; replaces vtrans).
__global__ __launch_bounds__(256) void proj_gemm(
    const short* __restrict__ xq, const short* __restrict__ xk, const short* __restrict__ xv,
    const short* __restrict__ wq, const short* __restrict__ wk, const short* __restrict__ wv,
    short* __restrict__ pq, short* __restrict__ pk, short* __restrict__ vt) {
  int z = blockIdx.z;
  const short* A  = (z == 0) ? xq : (z == 1) ? xk : xv;
  const short* Bt = (z == 0) ? wq : (z == 1) ? wk : wv;
  __shared__ __attribute__((aligned(16))) short As[128 * 32];
  __shared__ __attribute__((aligned(16))) short Bs[128 * 32];
  int t = threadIdx.x, l = t & 63, w = t >> 6;
  int wr = w >> 1, wc = w & 1;
  int lr = l & 15, lk = l >> 4;
  int bm0 = blockIdx.y * 128, bn0 = blockIdx.x * 128;
  const f32x4 Z = {0.f, 0.f, 0.f, 0.f};
  f32x4 acc[4][4];
  #pragma unroll
  for (int m = 0; m < 4; ++m)
    #pragma unroll
    for (int n = 0; n < 4; ++n) acc[m][n] = Z;

  int boff0 = w * 2 * 1024 + l * 16;
  int row0 = boff0 >> 6, ke0 = (boff0 & 63) >> 1;
  int boff1 = boff0 + 1024;
  int row1 = boff1 >> 6, ke1 = (boff1 & 63) >> 1;
  const short* ga0 = A + (size_t)(bm0 + row0) * 1024 + ke0;
  const short* ga1 = A + (size_t)(bm0 + row1) * 1024 + ke1;
  const short* gb0 = Bt + (size_t)(bn0 + row0) * 1024 + ke0;
  const short* gb1 = Bt + (size_t)(bn0 + row1) * 1024 + ke1;
  short* lA0 = As + (w * 2) * 512;     short* lA1 = As + (w * 2 + 1) * 512;
  short* lB0 = Bs + (w * 2) * 512;     short* lB1 = Bs + (w * 2 + 1) * 512;

  for (int kb = 0; kb < 1024; kb += 32) {
    GLD16(ga0 + kb, lA0);
    GLD16(ga1 + kb, lA1);
    GLD16(gb0 + kb, lB0);
    GLD16(gb1 + kb, lB1);
    __syncthreads();
    short8 a[4], bfr[4];
    #pragma unroll
    for (int m = 0; m < 4; ++m)
      a[m] = *(const short8*)(As + (wr * 64 + m * 16 + lr) * 32 + lk * 8);
    #pragma unroll
    for (int n = 0; n < 4; ++n)
      bfr[n] = *(const short8*)(Bs + (wc * 64 + n * 16 + lr) * 32 + lk * 8);
    __builtin_amdgcn_s_setprio(1);
    #pragma unroll
    for (int m = 0; m < 4; ++m)
      #pragma unroll
      for (int n = 0; n < 4; ++n)
        acc[m][n] = __builtin_amdgcn_mfma_f32_16x16x32_bf16(a[m], bfr[n], acc[m][n], 0, 0, 0);
    __builtin_amdgcn_s_setprio(0);
    __syncthreads();
  }
  #pragma unroll
  for (int m = 0; m < 4; ++m)
    #pragma unroll
    for (int n = 0; n < 4; ++n)
      #pragma unroll
      for (int i = 0; i < 4; ++i) {
        int r = bm0 + wr * 64 + m * 16 + lk * 4 + i;     // r = b*1024 + n1024
        int cc = bn0 + wc * 64 + n * 16 + lr;            // cc = h*64 + dv
        short val = f2bf(acc[m][n][i]);
        if (z == 2) {
          int b = r >> 10, n1024 = r & 1023, h = cc >> 6, dv = cc & 63;
          vt[(size_t)(h * 4 + b) * 65536 + (size_t)dv * 1024 + n1024] = val;
        } else {
          short* C = (z == 0) ? pq : pk;
          C[(size_t)r * 1024 + cc] = val;
        }
      }
}

// ------------- kernel 5: fused attention, two-pass, 8 waves, QBLK=128 -------------
// R12 structure + DISTANCE-2 prefetch: each chunk's global load is issued one full
// iteration before its ds_write (double reg-carry), so the ~600-900 cyc L3/HBM
// latency (pk/vt are cross-XCD, never local-L2) is covered by ~2 iterations.
#define PW 72
__global__ __launch_bounds__(512) void attn_fused(
    const short* __restrict__ pq, const short* __restrict__ pk, const short* __restrict__ vt,
    float* __restrict__ dout) {
  __shared__ __attribute__((aligned(16))) short Ks[2][64 * PW];
  __shared__ __attribute__((aligned(16))) short Vs[2][64 * PW];
  __shared__ __attribute__((aligned(16))) short Ps[128 * PW];
  int t = threadIdx.x, l = t & 63, w = t >> 6;
  int lr = l & 15, lk = l >> 4;
  int bid = blockIdx.x;
  int swz = (bid & 7) * 64 + (bid >> 3);           // XCD c -> hb in [c*8, c*8+8)
  int hb = swz >> 3, qt = swz & 7;
  int h = hb >> 2, b = hb & 3;                     // hb = h*B + b
  int q0 = qt * 128;
  const short* Qg = pq + (size_t)b * 1048576 + h * 64;
  const short* Kg = pk + (size_t)b * 1048576 + h * 64;
  const short* Vt = vt + (size_t)hb * 65536;
  float* attnp = dout + 4194304 + (size_t)hb * 1048576;
  const f32x4 Z = {0.f, 0.f, 0.f, 0.f};
  const float scale = 0.125f;
  int r0 = w * 16;
  int sj = t >> 3, sco = (t & 7) * 8;              // 512 threads cover 64x64 in one op

  // Q fragments direct from global (one-time)
  const short* qrow = Qg + (size_t)(q0 + r0 + lr) * 1024;
  short8 aq[2];
  aq[0] = *(const short8*)(qrow + lk * 8);
  aq[1] = *(const short8*)(qrow + 32 + lk * 8);

  short8 ka_w, ka_n, va_w, va_n;
  // pass-1 prologue: chunk0 -> Ks[0]; chunk1 held in regs (distance-2 carry)
  ka_w = *(const short8*)(Kg + (size_t)sj * 1024 + sco);
  *(short8*)(Ks[0] + sj * PW + sco) = ka_w;
  ka_w = *(const short8*)(Kg + (size_t)(64 + sj) * 1024 + sco);
  BAR();

  float s[4] = {0.f, 0.f, 0.f, 0.f};

  // ---- pass 1: sum of exp(scores) ----
  for (int nc = 0; nc < 16; ++nc) {
    int cur = nc & 1;
    if (nc < 14)   // issue load for chunk nc+2 (consumed by ds_write NEXT iter)
      ka_n = *(const short8*)(Kg + (size_t)((nc + 2) * 64 + sj) * 1024 + sco);
    f32x4 acc[4] = {Z, Z, Z, Z};
    __builtin_amdgcn_s_setprio(1);
    #pragma unroll
    for (int kk = 0; kk < 2; ++kk)
      #pragma unroll
      for (int n = 0; n < 4; ++n) {
        short8 bk = *(const short8*)(Ks[cur] + (n * 16 + lr) * PW + kk * 32 + lk * 8);
        acc[n] = __builtin_amdgcn_mfma_f32_16x16x32_bf16(aq[kk], bk, acc[n], 0, 0, 0);
      }
    __builtin_amdgcn_s_setprio(0);
    #pragma unroll
    for (int i = 0; i < 4; ++i)
      s[i] += __expf(acc[0][i] * scale) + __expf(acc[1][i] * scale) +
              __expf(acc[2][i] * scale) + __expf(acc[3][i] * scale);
    if (nc < 15) {  // write chunk nc+1 (loaded one iter ago) to the other buffer
      *(short8*)(Ks[cur ^ 1] + sj * PW + sco) = ka_w;
      ka_w = ka_n;
    }
    BAR();
  }
  #pragma unroll
  for (int i = 0; i < 4; ++i)
    #pragma unroll
    for (int msk = 1; msk < 16; msk <<= 1)
      s[i] += __shfl_xor(s[i], msk, 64);
  float inv[4];
  #pragma unroll
  for (int i = 0; i < 4; ++i) inv[i] = 1.0f / s[i];

  // pass-2 prologue: chunk0 (K,V) -> buf0; chunk1 held in regs
  ka_w = *(const short8*)(Kg + (size_t)sj * 1024 + sco);
  va_w = *(const short8*)(Vt + (size_t)sj * 1024 + sco);
  *(short8*)(Ks[0] + sj * PW + sco) = ka_w;
  *(short8*)(Vs[0] + sj * PW + sco) = va_w;
  ka_w = *(const short8*)(Kg + (size_t)(64 + sj) * 1024 + sco);
  va_w = *(const short8*)(Vt + (size_t)sj * 1024 + 64 + sco);
  BAR();

  // ---- pass 2: QK -> exp/Ps -> PV -> wide attn store ----
  f32x4 acco[4] = {Z, Z, Z, Z};
  int prow = r0 + (l >> 2), pseg = (l & 3) * 16;
  float* gpb = attnp + (size_t)(q0 + prow) * 1024 + pseg;
  for (int nc = 0; nc < 16; ++nc) {
    int cur = nc & 1;
    if (nc < 14) {
      ka_n = *(const short8*)(Kg + (size_t)((nc + 2) * 64 + sj) * 1024 + sco);
      va_n = *(const short8*)(Vt + (size_t)sj * 1024 + (nc + 2) * 64 + sco);
    }
    f32x4 acc[4] = {Z, Z, Z, Z};
    __builtin_amdgcn_s_setprio(1);
    #pragma unroll
    for (int kk = 0; kk < 2; ++kk)
      #pragma unroll
      for (int n = 0; n < 4; ++n) {
        short8 bk = *(const short8*)(Ks[cur] + (n * 16 + lr) * PW + kk * 32 + lk * 8);
        acc[n] = __builtin_amdgcn_mfma_f32_16x16x32_bf16(aq[kk], bk, acc[n], 0, 0, 0);
      }
    __builtin_amdgcn_s_setprio(0);
    // normalized P -> Ps (bf16, wave-private rows)
    #pragma unroll
    for (int n = 0; n < 4; ++n)
      #pragma unroll
      for (int i = 0; i < 4; ++i) {
        float p = __expf(acc[n][i] * scale) * inv[i];
        Ps[(r0 + lk * 4 + i) * PW + n * 16 + lr] = f2bf(p);
      }
    // PV first (MFMA covers the stores below): B from LDS-staged V
    #pragma unroll
    for (int kk = 0; kk < 2; ++kk) {
      short8 ap = *(const short8*)(Ps + (r0 + lr) * PW + kk * 32 + lk * 8);
      __builtin_amdgcn_s_setprio(1);
      #pragma unroll
      for (int f = 0; f < 4; ++f) {
        short8 bv = *(const short8*)(Vs[cur] + (f * 16 + lr) * PW + kk * 32 + lk * 8);
        acco[f] = __builtin_amdgcn_mfma_f32_16x16x32_bf16(ap, bv, acco[f], 0, 0, 0);
      }
      __builtin_amdgcn_s_setprio(0);
    }
    // wide attn store: 64B/lane contiguous from own wave's Ps rows
    {
      short8 p0 = *(const short8*)(Ps + prow * PW + pseg);
      short8 p1 = *(const short8*)(Ps + prow * PW + pseg + 8);
      float* gp = gpb + nc * 64;
      float4 f0 = {bf2f((unsigned short)p0[0]), bf2f((unsigned short)p0[1]),
                   bf2f((unsigned short)p0[2]), bf2f((unsigned short)p0[3])};
      float4 f1 = {bf2f((unsigned short)p0[4]), bf2f((unsigned short)p0[5]),
                   bf2f((unsigned short)p0[6]), bf2f((unsigned short)p0[7])};
      float4 f2 = {bf2f((unsigned short)p1[0]), bf2f((unsigned short)p1[1]),
                   bf2f((unsigned short)p1[2]), bf2f((unsigned short)p1[3])};
      float4 f3 = {bf2f((unsigned short)p1[4]), bf2f((unsigned short)p1[5]),
                   bf2f((unsigned short)p1[6]), bf2f((unsigned short)p1[7])};
      *(float4*)gp = f0; *(float4*)(gp + 4) = f1;
      *(float4*)(gp + 8) = f2; *(float4*)(gp + 12) = f3;
    }
    if (nc < 15) {
      *(short8*)(Ks[cur ^ 1] + sj * PW + sco) = ka_w;
      *(short8*)(Vs[cur ^ 1] + sj * PW + sco) = va_w;
      ka_w = ka_n; va_w = va_n;
    }
    BAR();
  }
  // out[b][n][h*64+dv] (f32)
  #pragma unroll
  for (int f = 0; f < 4; ++f)
    #pragma unroll
    for (int i = 0; i < 4; ++i) {
      int row = q0 + r0 + lk * 4 + i;
      int dv = f * 16 + lr;
      dout[(size_t)b * 1048576 + (size_t)row * 1024 + h * 64 + dv] = acco[f][i];
    }
}

extern "C" void kernel_launch(void* const* d_in, const int* in_sizes, int n_in,
                              void* d_out, int out_size, void* d_ws, size_t ws_size,
                              hipStream_t stream) {
  const void* big[3] = {0, 0, 0};
  const void* small[3] = {0, 0, 0};
  int nb = 0, ns = 0;
  for (int i = 0; i < n_in && i < 6; ++i) {
    if (in_sizes[i] == 4194304) { if (nb < 3) big[nb++] = d_in[i]; }
    else                        { if (ns < 3) small[ns++] = d_in[i]; }
  }
  const float *q, *k, *v, *wq, *wk, *wv;
  if (nb == 3 && ns == 3) {
    q = (const float*)big[0]; k = (const float*)big[1]; v = (const float*)big[2];
    wq = (const float*)small[0]; wk = (const float*)small[1]; wv = (const float*)small[2];
  } else {
    q = (const float*)d_in[0]; k = (const float*)d_in[1]; v = (const float*)d_in[2];
    wq = (const float*)d_in[3]; wk = (const float*)d_in[4]; wv = (const float*)d_in[5];
  }
  // workspace layout (shorts): total 32,505,856 shorts = 65 MB (validated size)
  short* W   = (short*)d_ws;
  short* xq  = W;
  short* xk  = W + 4194304;
  short* xv  = W + 8388608;
  short* wtq = W + 12582912;
  short* wtk = W + 13631488;
  short* wtv = W + 14680064;
  short* pq  = W + 15728640;
  short* pk  = W + 19922944;
  short* vt  = W + 28311552;
  float* out = (float*)d_out;

  cast_qkv<<<dim3(4096, 1, 3), 256, 0, stream>>>(q, k, v, xq, xk, xv);
  pack_w<<<dim3(1024, 1, 3), 256, 0, stream>>>(wq, wk, wv, wtq, wtk, wtv);
  proj_gemm<<<dim3(8, 32, 3), 256, 0, stream>>>(xq, xk, xv, wtq, wtk, wtv, pq, pk, vt);
  attn_fused<<<dim3(512), 512, 0, stream>>>(pq, pk, vt, out);
}

// Round 15
// 195.328 us; speedup vs baseline: 1.0678x; 1.0678x over previous
//
#include <hip/hip_runtime.h>

typedef short short8 __attribute__((ext_vector_type(8)));
typedef short short4_ __attribute__((ext_vector_type(4)));
typedef float f32x4 __attribute__((ext_vector_type(4)));

#define GLD16(gsrc, ldst) \
  __builtin_amdgcn_global_load_lds((__attribute__((address_space(1))) const void*)(gsrc), \
                                   (__attribute__((address_space(3))) void*)(ldst), 16, 0, 0)

// Raw barrier: wait only for LDS ops (dbuf handoff); global stores stay in flight.
#define BAR() do { asm volatile("s_waitcnt lgkmcnt(0)" ::: "memory"); \
  __builtin_amdgcn_sched_barrier(0); __builtin_amdgcn_s_barrier(); } while (0)

static __device__ __forceinline__ short f2bf(float f) {
  union { float f; unsigned u; } x; x.f = f;
  unsigned r = x.u + 0x7fffu + ((x.u >> 16) & 1u);
  return (short)(r >> 16);
}
static __device__ __forceinline__ float bf2f(unsigned short h) {
  union { unsigned u; float f; } x; x.u = ((unsigned)h) << 16;
  return x.f;
}

// ---------------- kernel 1: cast q,k,v f32 -> bf16 ----------------
__global__ __launch_bounds__(256) void cast_qkv(
    const float* __restrict__ q, const float* __restrict__ k, const float* __restrict__ v,
    short* __restrict__ xq, short* __restrict__ xk, short* __restrict__ xv) {
  int z = blockIdx.z;
  const float* s = (z == 0) ? q : (z == 1) ? k : v;
  short* d = (z == 0) ? xq : (z == 1) ? xk : xv;
  int i = (blockIdx.x * 256 + threadIdx.x) * 4;
  float4 f = *(const float4*)(s + i);
  short4_ o;
  o[0] = f2bf(f.x); o[1] = f2bf(f.y); o[2] = f2bf(f.z); o[3] = f2bf(f.w);
  *(short4_*)(d + i) = o;
}

// ------------- kernel 2: pack W (H,D,DK) f32 -> Bt (H*DK, D) bf16 -------------
__global__ __launch_bounds__(256) void pack_w(
    const float* __restrict__ wq, const float* __restrict__ wk, const float* __restrict__ wv,
    short* __restrict__ oq, short* __restrict__ ok, short* __restrict__ ov) {
  int z = blockIdx.z;
  const float* W = (z == 0) ? wq : (z == 1) ? wk : wv;
  short* o = ((z == 0) ? oq : (z == 1) ? ok : ov) + (size_t)blockIdx.x * 1024;
  int c = blockIdx.x;
  int h = c >> 6, kk = c & 63;
  const float* src = W + (size_t)h * 65536 + kk;  // + d*64
  #pragma unroll
  for (int it = 0; it < 4; ++it) {
    int d = it * 256 + threadIdx.x;
    o[d] = f2bf(src[(size_t)d * 64]);
  }
}

// ------------- kernel 3: projection GEMM (GLD16 staging, validated R11) -------------
__global__ __launch_bounds__(256) void proj_gemm(
    const short* __restrict__ xq, const short* __restrict__ xk, const short* __restrict__ xv,
    const short* __restrict__ wq, const short* __restrict__ wk, const short* __restrict__ wv,
    short* __restrict__ pq, short* __restrict__ pk, short* __restrict__ pv) {
  int z = blockIdx.z;
  const short* A  = (z == 0) ? xq : (z == 1) ? xk : xv;
  const short* Bt = (z == 0) ? wq : (z == 1) ? wk : wv;
  short* C        = (z == 0) ? pq : (z == 1) ? pk : pv;
  __shared__ __attribute__((aligned(16))) short As[128 * 32];
  __shared__ __attribute__((aligned(16))) short Bs[128 * 32];
  int t = threadIdx.x, l = t & 63, w = t >> 6;
  int wr = w >> 1, wc = w & 1;
  int lr = l & 15, lk = l >> 4;
  int bm0 = blockIdx.y * 128, bn0 = blockIdx.x * 128;
  const f32x4 Z = {0.f, 0.f, 0.f, 0.f};
  f32x4 acc[4][4];
  #pragma unroll
  for (int m = 0; m < 4; ++m)
    #pragma unroll
    for (int n = 0; n < 4; ++n) acc[m][n] = Z;

  int boff0 = w * 2 * 1024 + l * 16;
  int row0 = boff0 >> 6, ke0 = (boff0 & 63) >> 1;
  int boff1 = boff0 + 1024;
  int row1 = boff1 >> 6, ke1 = (boff1 & 63) >> 1;
  const short* ga0 = A + (size_t)(bm0 + row0) * 1024 + ke0;
  const short* ga1 = A + (size_t)(bm0 + row1) * 1024 + ke1;
  const short* gb0 = Bt + (size_t)(bn0 + row0) * 1024 + ke0;
  const short* gb1 = Bt + (size_t)(bn0 + row1) * 1024 + ke1;
  short* lA0 = As + (w * 2) * 512;     short* lA1 = As + (w * 2 + 1) * 512;
  short* lB0 = Bs + (w * 2) * 512;     short* lB1 = Bs + (w * 2 + 1) * 512;

  for (int kb = 0; kb < 1024; kb += 32) {
    GLD16(ga0 + kb, lA0);
    GLD16(ga1 + kb, lA1);
    GLD16(gb0 + kb, lB0);
    GLD16(gb1 + kb, lB1);
    __syncthreads();
    short8 a[4], bfr[4];
    #pragma unroll
    for (int m = 0; m < 4; ++m)
      a[m] = *(const short8*)(As + (wr * 64 + m * 16 + lr) * 32 + lk * 8);
    #pragma unroll
    for (int n = 0; n < 4; ++n)
      bfr[n] = *(const short8*)(Bs + (wc * 64 + n * 16 + lr) * 32 + lk * 8);
    __builtin_amdgcn_s_setprio(1);
    #pragma unroll
    for (int m = 0; m < 4; ++m)
      #pragma unroll
      for (int n = 0; n < 4; ++n)
        acc[m][n] = __builtin_amdgcn_mfma_f32_16x16x32_bf16(a[m], bfr[n], acc[m][n], 0, 0, 0);
    __builtin_amdgcn_s_setprio(0);
    __syncthreads();
  }
  #pragma unroll
  for (int m = 0; m < 4; ++m)
    #pragma unroll
    for (int n = 0; n < 4; ++n)
      #pragma unroll
      for (int i = 0; i < 4; ++i) {
        int r = bm0 + wr * 64 + m * 16 + lk * 4 + i;
        int cc = bn0 + wc * 64 + n * 16 + lr;
        C[(size_t)r * 1024 + cc] = f2bf(acc[m][n][i]);
      }
}

// ------------- kernel 4: V transpose  pv[b*N+n][h*64+dv] -> vt[hb][dv][n] -------------
__global__ __launch_bounds__(256) void vtrans(
    const short* __restrict__ pv, short* __restrict__ vt) {
  __shared__ short T[64 * 72];
  int t = threadIdx.x;
  int hb = blockIdx.y, h = hb >> 2, b = hb & 3;
  int n0 = blockIdx.x * 64;
  const short* src = pv + (size_t)b * 1048576 + (size_t)n0 * 1024 + h * 64;
  #pragma unroll
  for (int it = 0; it < 2; ++it) {
    int id = it * 256 + t;
    int row = id >> 3, seg = id & 7;
    *(short8*)(T + row * 72 + seg * 8) = *(const short8*)(src + (size_t)row * 1024 + seg * 8);
  }
  __syncthreads();
  short* dst = vt + (size_t)hb * 65536 + n0;
  #pragma unroll
  for (int it = 0; it < 2; ++it) {
    int id = it * 256 + t;
    int dv = id >> 3, seg = id & 7;
    short8 vv;
    #pragma unroll
    for (int jj = 0; jj < 8; ++jj) vv[jj] = T[(seg * 8 + jj) * 72 + dv];
    *(short8*)(dst + (size_t)dv * 1024 + seg * 8) = vv;
  }
}

// ------------- kernel 5: fused attention, 4 waves x 32 Q-rows (halved LDS traffic) -------------
// per block: (hb, 128 q-rows), 256 threads. Each wave owns TWO 16-row fragment
// sets (A/B) sharing every K/V LDS read -> LDS ops per output halve vs R11.
// K dbuf (both passes) + V dbuf (pass 2), distance-1 reg prefetch, BAR barriers,
// sum-only softmax (all validated).
#define PW 72
__global__ __launch_bounds__(256) void attn_fused(
    const short* __restrict__ pq, const short* __restrict__ pk, const short* __restrict__ vt,
    float* __restrict__ dout) {
  __shared__ __attribute__((aligned(16))) short Ks[2][64 * PW];
  __shared__ __attribute__((aligned(16))) short Vs[2][64 * PW];
  __shared__ __attribute__((aligned(16))) short Ps[128 * PW];
  int t = threadIdx.x, l = t & 63, w = t >> 6;
  int lr = l & 15, lk = l >> 4;
  int bid = blockIdx.x;
  int swz = (bid & 7) * 64 + (bid >> 3);           // XCD c -> hb in [c*8, c*8+8)
  int hb = swz >> 3, qt = swz & 7;
  int h = hb >> 2, b = hb & 3;                     // hb = h*B + b
  int q0 = qt * 128;
  const short* Qg = pq + (size_t)b * 1048576 + h * 64;
  const short* Kg = pk + (size_t)b * 1048576 + h * 64;
  const short* Vt = vt + (size_t)hb * 65536;
  float* attnp = dout + 4194304 + (size_t)hb * 1048576;
  const f32x4 Z = {0.f, 0.f, 0.f, 0.f};
  const float scale = 0.125f;
  int r0 = w * 32;                                 // wave owns rows r0..r0+31
  int sj = t >> 2, sc0 = (t & 3) * 16;             // staging: row sj, 2x short8 at sc0, sc0+8

  // Q fragments, two row sets, direct from global (one-time)
  const short* qrowA = Qg + (size_t)(q0 + r0 + lr) * 1024;
  const short* qrowB = Qg + (size_t)(q0 + r0 + 16 + lr) * 1024;
  short8 aqA[2], aqB[2];
  aqA[0] = *(const short8*)(qrowA + lk * 8);
  aqA[1] = *(const short8*)(qrowA + 32 + lk * 8);
  aqB[0] = *(const short8*)(qrowB + lk * 8);
  aqB[1] = *(const short8*)(qrowB + 32 + lk * 8);

  short8 ka0, ka1, va0, va1;
  // pass-1 prologue: stage K chunk 0 -> buf 0
  ka0 = *(const short8*)(Kg + (size_t)sj * 1024 + sc0);
  ka1 = *(const short8*)(Kg + (size_t)sj * 1024 + sc0 + 8);
  *(short8*)(Ks[0] + sj * PW + sc0) = ka0;
  *(short8*)(Ks[0] + sj * PW + sc0 + 8) = ka1;
  BAR();

  float sA[4] = {0.f, 0.f, 0.f, 0.f}, sB[4] = {0.f, 0.f, 0.f, 0.f};

  // ---- pass 1: sum of exp(scores), both row sets ----
  for (int nc = 0; nc < 16; ++nc) {
    int cur = nc & 1;
    if (nc < 15) {
      ka0 = *(const short8*)(Kg + (size_t)((nc + 1) * 64 + sj) * 1024 + sc0);
      ka1 = *(const short8*)(Kg + (size_t)((nc + 1) * 64 + sj) * 1024 + sc0 + 8);
    }
    f32x4 accA[4] = {Z, Z, Z, Z}, accB[4] = {Z, Z, Z, Z};
    __builtin_amdgcn_s_setprio(1);
    #pragma unroll
    for (int kk = 0; kk < 2; ++kk)
      #pragma unroll
      for (int n = 0; n < 4; ++n) {
        short8 bk = *(const short8*)(Ks[cur] + (n * 16 + lr) * PW + kk * 32 + lk * 8);
        accA[n] = __builtin_amdgcn_mfma_f32_16x16x32_bf16(aqA[kk], bk, accA[n], 0, 0, 0);
        accB[n] = __builtin_amdgcn_mfma_f32_16x16x32_bf16(aqB[kk], bk, accB[n], 0, 0, 0);
      }
    __builtin_amdgcn_s_setprio(0);
    #pragma unroll
    for (int i = 0; i < 4; ++i) {
      sA[i] += __expf(accA[0][i] * scale) + __expf(accA[1][i] * scale) +
               __expf(accA[2][i] * scale) + __expf(accA[3][i] * scale);
      sB[i] += __expf(accB[0][i] * scale) + __expf(accB[1][i] * scale) +
               __expf(accB[2][i] * scale) + __expf(accB[3][i] * scale);
    }
    if (nc < 15) {
      *(short8*)(Ks[cur ^ 1] + sj * PW + sc0) = ka0;
      *(short8*)(Ks[cur ^ 1] + sj * PW + sc0 + 8) = ka1;
    }
    BAR();
  }
  #pragma unroll
  for (int i = 0; i < 4; ++i)
    #pragma unroll
    for (int msk = 1; msk < 16; msk <<= 1) {
      sA[i] += __shfl_xor(sA[i], msk, 64);
      sB[i] += __shfl_xor(sB[i], msk, 64);
    }
  float invA[4], invB[4];
  #pragma unroll
  for (int i = 0; i < 4; ++i) { invA[i] = 1.0f / sA[i]; invB[i] = 1.0f / sB[i]; }

  // pass-2 prologue: chunk 0 (K and V) -> buf 0
  ka0 = *(const short8*)(Kg + (size_t)sj * 1024 + sc0);
  ka1 = *(const short8*)(Kg + (size_t)sj * 1024 + sc0 + 8);
  va0 = *(const short8*)(Vt + (size_t)sj * 1024 + sc0);
  va1 = *(const short8*)(Vt + (size_t)sj * 1024 + sc0 + 8);
  *(short8*)(Ks[0] + sj * PW + sc0) = ka0;
  *(short8*)(Ks[0] + sj * PW + sc0 + 8) = ka1;
  *(short8*)(Vs[0] + sj * PW + sc0) = va0;
  *(short8*)(Vs[0] + sj * PW + sc0 + 8) = va1;
  BAR();

  // ---- pass 2: QK -> exp/Ps -> PV -> wide attn store ----
  f32x4 accoA[4] = {Z, Z, Z, Z}, accoB[4] = {Z, Z, Z, Z};
  int prow = r0 + (l >> 1), pseg = (l & 1) * 32;   // 32 rows x 2 half-rows per wave
  float* gpb = attnp + (size_t)(q0 + prow) * 1024 + pseg;
  for (int nc = 0; nc < 16; ++nc) {
    int cur = nc & 1;
    if (nc < 15) {
      ka0 = *(const short8*)(Kg + (size_t)((nc + 1) * 64 + sj) * 1024 + sc0);
      ka1 = *(const short8*)(Kg + (size_t)((nc + 1) * 64 + sj) * 1024 + sc0 + 8);
      va0 = *(const short8*)(Vt + (size_t)sj * 1024 + (nc + 1) * 64 + sc0);
      va1 = *(const short8*)(Vt + (size_t)sj * 1024 + (nc + 1) * 64 + sc0 + 8);
    }
    f32x4 accA[4] = {Z, Z, Z, Z}, accB[4] = {Z, Z, Z, Z};
    __builtin_amdgcn_s_setprio(1);
    #pragma unroll
    for (int kk = 0; kk < 2; ++kk)
      #pragma unroll
      for (int n = 0; n < 4; ++n) {
        short8 bk = *(const short8*)(Ks[cur] + (n * 16 + lr) * PW + kk * 32 + lk * 8);
        accA[n] = __builtin_amdgcn_mfma_f32_16x16x32_bf16(aqA[kk], bk, accA[n], 0, 0, 0);
        accB[n] = __builtin_amdgcn_mfma_f32_16x16x32_bf16(aqB[kk], bk, accB[n], 0, 0, 0);
      }
    __builtin_amdgcn_s_setprio(0);
    // normalized P -> Ps (bf16, wave-private rows), both sets
    #pragma unroll
    for (int n = 0; n < 4; ++n)
      #pragma unroll
      for (int i = 0; i < 4; ++i) {
        float pA = __expf(accA[n][i] * scale) * invA[i];
        float pB = __expf(accB[n][i] * scale) * invB[i];
        Ps[(r0 + lk * 4 + i) * PW + n * 16 + lr] = f2bf(pA);
        Ps[(r0 + 16 + lk * 4 + i) * PW + n * 16 + lr] = f2bf(pB);
      }
    // PV: shared bv reads feed both row sets
    #pragma unroll
    for (int kk = 0; kk < 2; ++kk) {
      short8 apA = *(const short8*)(Ps + (r0 + lr) * PW + kk * 32 + lk * 8);
      short8 apB = *(const short8*)(Ps + (r0 + 16 + lr) * PW + kk * 32 + lk * 8);
      __builtin_amdgcn_s_setprio(1);
      #pragma unroll
      for (int f = 0; f < 4; ++f) {
        short8 bv = *(const short8*)(Vs[cur] + (f * 16 + lr) * PW + kk * 32 + lk * 8);
        accoA[f] = __builtin_amdgcn_mfma_f32_16x16x32_bf16(apA, bv, accoA[f], 0, 0, 0);
        accoB[f] = __builtin_amdgcn_mfma_f32_16x16x32_bf16(apB, bv, accoB[f], 0, 0, 0);
      }
      __builtin_amdgcn_s_setprio(0);
    }
    // wide attn store: lane covers 128B of one row (8 float4s)
    {
      float* gp = gpb + nc * 64;
      #pragma unroll
      for (int j = 0; j < 4; ++j) {
        short8 p = *(const short8*)(Ps + prow * PW + pseg + j * 8);
        float4 fo0 = {bf2f((unsigned short)p[0]), bf2f((unsigned short)p[1]),
                      bf2f((unsigned short)p[2]), bf2f((unsigned short)p[3])};
        float4 fo1 = {bf2f((unsigned short)p[4]), bf2f((unsigned short)p[5]),
                      bf2f((unsigned short)p[6]), bf2f((unsigned short)p[7])};
        *(float4*)(gp + j * 8) = fo0;
        *(float4*)(gp + j * 8 + 4) = fo1;
      }
    }
    if (nc < 15) {
      *(short8*)(Ks[cur ^ 1] + sj * PW + sc0) = ka0;
      *(short8*)(Ks[cur ^ 1] + sj * PW + sc0 + 8) = ka1;
      *(short8*)(Vs[cur ^ 1] + sj * PW + sc0) = va0;
      *(short8*)(Vs[cur ^ 1] + sj * PW + sc0 + 8) = va1;
    }
    BAR();
  }
  // out[b][n][h*64+dv] (f32), both row sets
  #pragma unroll
  for (int f = 0; f < 4; ++f)
    #pragma unroll
    for (int i = 0; i < 4; ++i) {
      int rowA = q0 + r0 + lk * 4 + i;
      int dv = f * 16 + lr;
      dout[(size_t)b * 1048576 + (size_t)rowA * 1024 + h * 64 + dv] = accoA[f][i];
      dout[(size_t)b * 1048576 + (size_t)(rowA + 16) * 1024 + h * 64 + dv] = accoB[f][i];
    }
}

extern "C" void kernel_launch(void* const* d_in, const int* in_sizes, int n_in,
                              void* d_out, int out_size, void* d_ws, size_t ws_size,
                              hipStream_t stream) {
  const void* big[3] = {0, 0, 0};
  const void* small[3] = {0, 0, 0};
  int nb = 0, ns = 0;
  for (int i = 0; i < n_in && i < 6; ++i) {
    if (in_sizes[i] == 4194304) { if (nb < 3) big[nb++] = d_in[i]; }
    else                        { if (ns < 3) small[ns++] = d_in[i]; }
  }
  const float *q, *k, *v, *wq, *wk, *wv;
  if (nb == 3 && ns == 3) {
    q = (const float*)big[0]; k = (const float*)big[1]; v = (const float*)big[2];
    wq = (const float*)small[0]; wk = (const float*)small[1]; wv = (const float*)small[2];
  } else {
    q = (const float*)d_in[0]; k = (const float*)d_in[1]; v = (const float*)d_in[2];
    wq = (const float*)d_in[3]; wk = (const float*)d_in[4]; wv = (const float*)d_in[5];
  }
  // workspace layout (shorts): total 32,505,856 shorts = 65 MB (validated size)
  short* W   = (short*)d_ws;
  short* xq  = W;
  short* xk  = W + 4194304;
  short* xv  = W + 8388608;
  short* wtq = W + 12582912;
  short* wtk = W + 13631488;
  short* wtv = W + 14680064;
  short* pq  = W + 15728640;
  short* pk  = W + 19922944;
  short* pv  = W + 24117248;
  short* vt  = W + 28311552;
  float* out = (float*)d_out;

  cast_qkv<<<dim3(4096, 1, 3), 256, 0, stream>>>(q, k, v, xq, xk, xv);
  pack_w<<<dim3(1024, 1, 3), 256, 0, stream>>>(wq, wk, wv, wtq, wtk, wtv);
  proj_gemm<<<dim3(8, 32, 3), 256, 0, stream>>>(xq, xk, xv, wtq, wtk, wtv, pq, pk, pv);
  vtrans<<<dim3(16, 64), 256, 0, stream>>>(pv, vt);
  attn_fused<<<dim3(512), 256, 0, stream>>>(pq, pk, vt, out);
}

// Round 16
// 189.749 us; speedup vs baseline: 1.0992x; 1.0294x over previous
//
#include <hip/hip_runtime.h>

typedef short short8 __attribute__((ext_vector_type(8)));
typedef short short4_ __attribute__((ext_vector_type(4)));
typedef float f32x4 __attribute__((ext_vector_type(4)));

#define GLD16(gsrc, ldst) \
  __builtin_amdgcn_global_load_lds((__attribute__((address_space(1))) const void*)(gsrc), \
                                   (__attribute__((address_space(3))) void*)(ldst), 16, 0, 0)

// Raw barrier: wait only for LDS ops (dbuf handoff); global stores stay in flight.
#define BAR() do { asm volatile("s_waitcnt lgkmcnt(0)" ::: "memory"); \
  __builtin_amdgcn_sched_barrier(0); __builtin_amdgcn_s_barrier(); } while (0)

static __device__ __forceinline__ short f2bf(float f) {
  union { float f; unsigned u; } x; x.f = f;
  unsigned r = x.u + 0x7fffu + ((x.u >> 16) & 1u);
  return (short)(r >> 16);
}
static __device__ __forceinline__ float bf2f(unsigned short h) {
  union { unsigned u; float f; } x; x.u = ((unsigned)h) << 16;
  return x.f;
}

// ---------------- kernel 1: cast q,k,v f32 -> bf16  AND pack weights (merged) ----------------
__global__ __launch_bounds__(256) void cast_pack(
    const float* __restrict__ q, const float* __restrict__ k, const float* __restrict__ v,
    const float* __restrict__ wq, const float* __restrict__ wk, const float* __restrict__ wv,
    short* __restrict__ xq, short* __restrict__ xk, short* __restrict__ xv,
    short* __restrict__ oq, short* __restrict__ ok, short* __restrict__ ov) {
  int z = blockIdx.z;
  if (blockIdx.x < 4096) {             // cast q/k/v
    const float* s = (z == 0) ? q : (z == 1) ? k : v;
    short* d = (z == 0) ? xq : (z == 1) ? xk : xv;
    int i = (blockIdx.x * 256 + threadIdx.x) * 4;
    float4 f = *(const float4*)(s + i);
    short4_ o;
    o[0] = f2bf(f.x); o[1] = f2bf(f.y); o[2] = f2bf(f.z); o[3] = f2bf(f.w);
    *(short4_*)(d + i) = o;
  } else {                             // pack W (H,D,DK) -> Bt (H*DK, D)
    const float* W = (z == 0) ? wq : (z == 1) ? wk : wv;
    int c = blockIdx.x - 4096;
    short* o = ((z == 0) ? oq : (z == 1) ? ok : ov) + (size_t)c * 1024;
    int h = c >> 6, kk = c & 63;
    const float* src = W + (size_t)h * 65536 + kk;  // + d*64
    #pragma unroll
    for (int it = 0; it < 4; ++it) {
      int d = it * 256 + threadIdx.x;
      o[d] = f2bf(src[(size_t)d * 64]);
    }
  }
}

// ------------- kernel 3: projection GEMM, BK=64 as two half-tiles -------------
// Same 64B-row LDS geometry as the validated BK=32 kernel (no new bank behavior);
// 32 MFMA per barrier-pair (vs 16), 16 K-iterations (vs 32). LDS 32 KB.
__global__ __launch_bounds__(256) void proj_gemm(
    const short* __restrict__ xq, const short* __restrict__ xk, const short* __restrict__ xv,
    const short* __restrict__ wq, const short* __restrict__ wk, const short* __restrict__ wv,
    short* __restrict__ pq, short* __restrict__ pk, short* __restrict__ pv) {
  int z = blockIdx.z;
  const short* A  = (z == 0) ? xq : (z == 1) ? xk : xv;
  const short* Bt = (z == 0) ? wq : (z == 1) ? wk : wv;
  short* C        = (z == 0) ? pq : (z == 1) ? pk : pv;
  __shared__ __attribute__((aligned(16))) short As[2][128 * 32];
  __shared__ __attribute__((aligned(16))) short Bs[2][128 * 32];
  int t = threadIdx.x, l = t & 63, w = t >> 6;
  int wr = w >> 1, wc = w & 1;
  int lr = l & 15, lk = l >> 4;
  int bm0 = blockIdx.y * 128, bn0 = blockIdx.x * 128;
  const f32x4 Z = {0.f, 0.f, 0.f, 0.f};
  f32x4 acc[4][4];
  #pragma unroll
  for (int m = 0; m < 4; ++m)
    #pragma unroll
    for (int n = 0; n < 4; ++n) acc[m][n] = Z;

  // staging geometry (identical per half): wave w covers LDS bytes [(w*2+i)*1024)
  int boff0 = w * 2 * 1024 + l * 16;
  int row0 = boff0 >> 6, ke0 = (boff0 & 63) >> 1;
  int boff1 = boff0 + 1024;
  int row1 = boff1 >> 6, ke1 = (boff1 & 63) >> 1;
  const short* ga0 = A + (size_t)(bm0 + row0) * 1024 + ke0;
  const short* ga1 = A + (size_t)(bm0 + row1) * 1024 + ke1;
  const short* gb0 = Bt + (size_t)(bn0 + row0) * 1024 + ke0;
  const short* gb1 = Bt + (size_t)(bn0 + row1) * 1024 + ke1;
  int lo = (w * 2) * 512, lo1 = (w * 2 + 1) * 512;

  for (int kb = 0; kb < 1024; kb += 64) {
    #pragma unroll
    for (int hh = 0; hh < 2; ++hh) {
      int kc = kb + hh * 32;
      GLD16(ga0 + kc, As[hh] + lo);
      GLD16(ga1 + kc, As[hh] + lo1);
      GLD16(gb0 + kc, Bs[hh] + lo);
      GLD16(gb1 + kc, Bs[hh] + lo1);
    }
    __syncthreads();
    #pragma unroll
    for (int hh = 0; hh < 2; ++hh) {
      short8 a[4], bfr[4];
      #pragma unroll
      for (int m = 0; m < 4; ++m)
        a[m] = *(const short8*)(As[hh] + (wr * 64 + m * 16 + lr) * 32 + lk * 8);
      #pragma unroll
      for (int n = 0; n < 4; ++n)
        bfr[n] = *(const short8*)(Bs[hh] + (wc * 64 + n * 16 + lr) * 32 + lk * 8);
      __builtin_amdgcn_s_setprio(1);
      #pragma unroll
      for (int m = 0; m < 4; ++m)
        #pragma unroll
        for (int n = 0; n < 4; ++n)
          acc[m][n] = __builtin_amdgcn_mfma_f32_16x16x32_bf16(a[m], bfr[n], acc[m][n], 0, 0, 0);
      __builtin_amdgcn_s_setprio(0);
    }
    __syncthreads();
  }
  #pragma unroll
  for (int m = 0; m < 4; ++m)
    #pragma unroll
    for (int n = 0; n < 4; ++n)
      #pragma unroll
      for (int i = 0; i < 4; ++i) {
        int r = bm0 + wr * 64 + m * 16 + lk * 4 + i;
        int cc = bn0 + wc * 64 + n * 16 + lr;
        C[(size_t)r * 1024 + cc] = f2bf(acc[m][n][i]);
      }
}

// ------------- kernel 4: V transpose  pv[b*N+n][h*64+dv] -> vt[hb][dv][n] -------------
__global__ __launch_bounds__(256) void vtrans(
    const short* __restrict__ pv, short* __restrict__ vt) {
  __shared__ short T[64 * 72];
  int t = threadIdx.x;
  int hb = blockIdx.y, h = hb >> 2, b = hb & 3;
  int n0 = blockIdx.x * 64;
  const short* src = pv + (size_t)b * 1048576 + (size_t)n0 * 1024 + h * 64;
  #pragma unroll
  for (int it = 0; it < 2; ++it) {
    int id = it * 256 + t;
    int row = id >> 3, seg = id & 7;
    *(short8*)(T + row * 72 + seg * 8) = *(const short8*)(src + (size_t)row * 1024 + seg * 8);
  }
  __syncthreads();
  short* dst = vt + (size_t)hb * 65536 + n0;
  #pragma unroll
  for (int it = 0; it < 2; ++it) {
    int id = it * 256 + t;
    int dv = id >> 3, seg = id & 7;
    short8 vv;
    #pragma unroll
    for (int jj = 0; jj < 8; ++jj) vv[jj] = T[(seg * 8 + jj) * 72 + dv];
    *(short8*)(dst + (size_t)dv * 1024 + seg * 8) = vv;
  }
}

// ------------- kernel 5: fused attention, two-pass, 8 waves, QBLK=128 (exact R11) -------------
#define PW 72
__global__ __launch_bounds__(512) void attn_fused(
    const short* __restrict__ pq, const short* __restrict__ pk, const short* __restrict__ vt,
    float* __restrict__ dout) {
  __shared__ __attribute__((aligned(16))) short Ks[2][64 * PW];
  __shared__ __attribute__((aligned(16))) short Vs[2][64 * PW];
  __shared__ __attribute__((aligned(16))) short Ps[128 * PW];
  int t = threadIdx.x, l = t & 63, w = t >> 6;
  int lr = l & 15, lk = l >> 4;
  int bid = blockIdx.x;
  int swz = (bid & 7) * 64 + (bid >> 3);           // XCD c -> hb in [c*8, c*8+8)
  int hb = swz >> 3, qt = swz & 7;
  int h = hb >> 2, b = hb & 3;                     // hb = h*B + b
  int q0 = qt * 128;
  const short* Qg = pq + (size_t)b * 1048576 + h * 64;
  const short* Kg = pk + (size_t)b * 1048576 + h * 64;
  const short* Vt = vt + (size_t)hb * 65536;
  float* attnp = dout + 4194304 + (size_t)hb * 1048576;
  const f32x4 Z = {0.f, 0.f, 0.f, 0.f};
  const float scale = 0.125f;
  int r0 = w * 16;
  int sj = t >> 3, sco = (t & 7) * 8;              // 512 threads cover 64x64 in one op

  // Q fragments direct from global (one-time)
  const short* qrow = Qg + (size_t)(q0 + r0 + lr) * 1024;
  short8 aq[2];
  aq[0] = *(const short8*)(qrow + lk * 8);
  aq[1] = *(const short8*)(qrow + 32 + lk * 8);

  short8 ka, va;
  // prologue: stage K chunk 0 -> buf 0
  ka = *(const short8*)(Kg + (size_t)sj * 1024 + sco);
  *(short8*)(Ks[0] + sj * PW + sco) = ka;
  BAR();

  float s[4] = {0.f, 0.f, 0.f, 0.f};

  // ---- pass 1: sum of exp(scores) ----
  for (int nc = 0; nc < 16; ++nc) {
    int cur = nc & 1;
    if (nc < 15)
      ka = *(const short8*)(Kg + (size_t)((nc + 1) * 64 + sj) * 1024 + sco);
    f32x4 acc[4] = {Z, Z, Z, Z};
    __builtin_amdgcn_s_setprio(1);
    #pragma unroll
    for (int kk = 0; kk < 2; ++kk)
      #pragma unroll
      for (int n = 0; n < 4; ++n) {
        short8 bk = *(const short8*)(Ks[cur] + (n * 16 + lr) * PW + kk * 32 + lk * 8);
        acc[n] = __builtin_amdgcn_mfma_f32_16x16x32_bf16(aq[kk], bk, acc[n], 0, 0, 0);
      }
    __builtin_amdgcn_s_setprio(0);
    #pragma unroll
    for (int i = 0; i < 4; ++i)
      s[i] += __expf(acc[0][i] * scale) + __expf(acc[1][i] * scale) +
              __expf(acc[2][i] * scale) + __expf(acc[3][i] * scale);
    if (nc < 15)
      *(short8*)(Ks[cur ^ 1] + sj * PW + sco) = ka;
    BAR();
  }
  #pragma unroll
  for (int i = 0; i < 4; ++i)
    #pragma unroll
    for (int msk = 1; msk < 16; msk <<= 1)
      s[i] += __shfl_xor(s[i], msk, 64);
  float inv[4];
  #pragma unroll
  for (int i = 0; i < 4; ++i) inv[i] = 1.0f / s[i];

  // re-prime buf 0 with chunk 0 (K and V)
  ka = *(const short8*)(Kg + (size_t)sj * 1024 + sco);
  va = *(const short8*)(Vt + (size_t)sj * 1024 + sco);
  *(short8*)(Ks[0] + sj * PW + sco) = ka;
  *(short8*)(Vs[0] + sj * PW + sco) = va;
  BAR();

  // ---- pass 2: QK -> exp/Ps -> PV -> wide attn store ----
  f32x4 acco[4] = {Z, Z, Z, Z};
  int prow = r0 + (l >> 2), pseg = (l & 3) * 16;
  float* gpb = attnp + (size_t)(q0 + prow) * 1024 + pseg;
  for (int nc = 0; nc < 16; ++nc) {
    int cur = nc & 1;
    if (nc < 15) {
      ka = *(const short8*)(Kg + (size_t)((nc + 1) * 64 + sj) * 1024 + sco);
      va = *(const short8*)(Vt + (size_t)sj * 1024 + (nc + 1) * 64 + sco);
    }
    f32x4 acc[4] = {Z, Z, Z, Z};
    __builtin_amdgcn_s_setprio(1);
    #pragma unroll
    for (int kk = 0; kk < 2; ++kk)
      #pragma unroll
      for (int n = 0; n < 4; ++n) {
        short8 bk = *(const short8*)(Ks[cur] + (n * 16 + lr) * PW + kk * 32 + lk * 8);
        acc[n] = __builtin_amdgcn_mfma_f32_16x16x32_bf16(aq[kk], bk, acc[n], 0, 0, 0);
      }
    __builtin_amdgcn_s_setprio(0);
    // normalized P -> Ps (bf16, wave-private rows)
    #pragma unroll
    for (int n = 0; n < 4; ++n)
      #pragma unroll
      for (int i = 0; i < 4; ++i) {
        float p = __expf(acc[n][i] * scale) * inv[i];
        Ps[(r0 + lk * 4 + i) * PW + n * 16 + lr] = f2bf(p);
      }
    // PV first (MFMA covers the stores below): B from LDS-staged V
    #pragma unroll
    for (int kk = 0; kk < 2; ++kk) {
      short8 ap = *(const short8*)(Ps + (r0 + lr) * PW + kk * 32 + lk * 8);
      __builtin_amdgcn_s_setprio(1);
      #pragma unroll
      for (int f = 0; f < 4; ++f) {
        short8 bv = *(const short8*)(Vs[cur] + (f * 16 + lr) * PW + kk * 32 + lk * 8);
        acco[f] = __builtin_amdgcn_mfma_f32_16x16x32_bf16(ap, bv, acco[f], 0, 0, 0);
      }
      __builtin_amdgcn_s_setprio(0);
    }
    // wide attn store: 64B/lane contiguous from own wave's Ps rows
    {
      short8 p0 = *(const short8*)(Ps + prow * PW + pseg);
      short8 p1 = *(const short8*)(Ps + prow * PW + pseg + 8);
      float* gp = gpb + nc * 64;
      float4 f0 = {bf2f((unsigned short)p0[0]), bf2f((unsigned short)p0[1]),
                   bf2f((unsigned short)p0[2]), bf2f((unsigned short)p0[3])};
      float4 f1 = {bf2f((unsigned short)p0[4]), bf2f((unsigned short)p0[5]),
                   bf2f((unsigned short)p0[6]), bf2f((unsigned short)p0[7])};
      float4 f2 = {bf2f((unsigned short)p1[0]), bf2f((unsigned short)p1[1]),
                   bf2f((unsigned short)p1[2]), bf2f((unsigned short)p1[3])};
      float4 f3 = {bf2f((unsigned short)p1[4]), bf2f((unsigned short)p1[5]),
                   bf2f((unsigned short)p1[6]), bf2f((unsigned short)p1[7])};
      *(float4*)gp = f0; *(float4*)(gp + 4) = f1;
      *(float4*)(gp + 8) = f2; *(float4*)(gp + 12) = f3;
    }
    if (nc < 15) {
      *(short8*)(Ks[cur ^ 1] + sj * PW + sco) = ka;
      *(short8*)(Vs[cur ^ 1] + sj * PW + sco) = va;
    }
    BAR();
  }
  // out[b][n][h*64+dv] (f32)
  #pragma unroll
  for (int f = 0; f < 4; ++f)
    #pragma unroll
    for (int i = 0; i < 4; ++i) {
      int row = q0 + r0 + lk * 4 + i;
      int dv = f * 16 + lr;
      dout[(size_t)b * 1048576 + (size_t)row * 1024 + h * 64 + dv] = acco[f][i];
    }
}

extern "C" void kernel_launch(void* const* d_in, const int* in_sizes, int n_in,
                              void* d_out, int out_size, void* d_ws, size_t ws_size,
                              hipStream_t stream) {
  const void* big[3] = {0, 0, 0};
  const void* small[3] = {0, 0, 0};
  int nb = 0, ns = 0;
  for (int i = 0; i < n_in && i < 6; ++i) {
    if (in_sizes[i] == 4194304) { if (nb < 3) big[nb++] = d_in[i]; }
    else                        { if (ns < 3) small[ns++] = d_in[i]; }
  }
  const float *q, *k, *v, *wq, *wk, *wv;
  if (nb == 3 && ns == 3) {
    q = (const float*)big[0]; k = (const float*)big[1]; v = (const float*)big[2];
    wq = (const float*)small[0]; wk = (const float*)small[1]; wv = (const float*)small[2];
  } else {
    q = (const float*)d_in[0]; k = (const float*)d_in[1]; v = (const float*)d_in[2];
    wq = (const float*)d_in[3]; wk = (const float*)d_in[4]; wv = (const float*)d_in[5];
  }
  // workspace layout (shorts): total 32,505,856 shorts = 65 MB (validated size)
  short* W   = (short*)d_ws;
  short* xq  = W;
  short* xk  = W + 4194304;
  short* xv  = W + 8388608;
  short* wtq = W + 12582912;
  short* wtk = W + 13631488;
  short* wtv = W + 14680064;
  short* pq  = W + 15728640;
  short* pk  = W + 19922944;
  short* pv  = W + 24117248;
  short* vt  = W + 28311552;
  float* out = (float*)d_out;

  cast_pack<<<dim3(5120, 1, 3), 256, 0, stream>>>(q, k, v, wq, wk, wv,
                                                  xq, xk, xv, wtq, wtk, wtv);
  proj_gemm<<<dim3(8, 32, 3), 256, 0, stream>>>(xq, xk, xv, wtq, wtk, wtv, pq, pk, pv);
  vtrans<<<dim3(16, 64), 256, 0, stream>>>(pv, vt);
  attn_fused<<<dim3(512), 512, 0, stream>>>(pq, pk, vt, out);
}

// Round 17
// 155.823 us; speedup vs baseline: 1.3385x; 1.2177x over previous
//
#include <hip/hip_runtime.h>

typedef short short8 __attribute__((ext_vector_type(8)));
typedef short short4_ __attribute__((ext_vector_type(4)));
typedef float f32x4 __attribute__((ext_vector_type(4)));

#define GLD16(gsrc, ldst) \
  __builtin_amdgcn_global_load_lds((__attribute__((address_space(1))) const void*)(gsrc), \
                                   (__attribute__((address_space(3))) void*)(ldst), 16, 0, 0)

// Raw barrier: wait only for LDS ops (dbuf handoff); global stores stay in flight.
#define BAR() do { asm volatile("s_waitcnt lgkmcnt(0)" ::: "memory"); \
  __builtin_amdgcn_sched_barrier(0); __builtin_amdgcn_s_barrier(); } while (0)

static __device__ __forceinline__ short f2bf(float f) {
  union { float f; unsigned u; } x; x.f = f;
  unsigned r = x.u + 0x7fffu + ((x.u >> 16) & 1u);
  return (short)(r >> 16);
}
static __device__ __forceinline__ float bf2f(unsigned short h) {
  union { unsigned u; float f; } x; x.u = ((unsigned)h) << 16;
  return x.f;
}

// ---------------- kernel 1: cast q,k,v f32 -> bf16  AND pack weights (merged) ----------------
__global__ __launch_bounds__(256) void cast_pack(
    const float* __restrict__ q, const float* __restrict__ k, const float* __restrict__ v,
    const float* __restrict__ wq, const float* __restrict__ wk, const float* __restrict__ wv,
    short* __restrict__ xq, short* __restrict__ xk, short* __restrict__ xv,
    short* __restrict__ oq, short* __restrict__ ok, short* __restrict__ ov) {
  int z = blockIdx.z;
  if (blockIdx.x < 4096) {             // cast q/k/v
    const float* s = (z == 0) ? q : (z == 1) ? k : v;
    short* d = (z == 0) ? xq : (z == 1) ? xk : xv;
    int i = (blockIdx.x * 256 + threadIdx.x) * 4;
    float4 f = *(const float4*)(s + i);
    short4_ o;
    o[0] = f2bf(f.x); o[1] = f2bf(f.y); o[2] = f2bf(f.z); o[3] = f2bf(f.w);
    *(short4_*)(d + i) = o;
  } else {                             // pack W (H,D,DK) -> Bt (H*DK, D)
    const float* W = (z == 0) ? wq : (z == 1) ? wk : wv;
    int c = blockIdx.x - 4096;
    short* o = ((z == 0) ? oq : (z == 1) ? ok : ov) + (size_t)c * 1024;
    int h = c >> 6, kk = c & 63;
    const float* src = W + (size_t)h * 65536 + kk;  // + d*64
    #pragma unroll
    for (int it = 0; it < 4; ++it) {
      int d = it * 256 + threadIdx.x;
      o[d] = f2bf(src[(size_t)d * 64]);
    }
  }
}

// ------------- kernel 3: projection GEMM, BK=64 as two half-tiles (R16, validated) -------------
__global__ __launch_bounds__(256) void proj_gemm(
    const short* __restrict__ xq, const short* __restrict__ xk, const short* __restrict__ xv,
    const short* __restrict__ wq, const short* __restrict__ wk, const short* __restrict__ wv,
    short* __restrict__ pq, short* __restrict__ pk, short* __restrict__ pv) {
  int z = blockIdx.z;
  const short* A  = (z == 0) ? xq : (z == 1) ? xk : xv;
  const short* Bt = (z == 0) ? wq : (z == 1) ? wk : wv;
  short* C        = (z == 0) ? pq : (z == 1) ? pk : pv;
  __shared__ __attribute__((aligned(16))) short As[2][128 * 32];
  __shared__ __attribute__((aligned(16))) short Bs[2][128 * 32];
  int t = threadIdx.x, l = t & 63, w = t >> 6;
  int wr = w >> 1, wc = w & 1;
  int lr = l & 15, lk = l >> 4;
  int bm0 = blockIdx.y * 128, bn0 = blockIdx.x * 128;
  const f32x4 Z = {0.f, 0.f, 0.f, 0.f};
  f32x4 acc[4][4];
  #pragma unroll
  for (int m = 0; m < 4; ++m)
    #pragma unroll
    for (int n = 0; n < 4; ++n) acc[m][n] = Z;

  int boff0 = w * 2 * 1024 + l * 16;
  int row0 = boff0 >> 6, ke0 = (boff0 & 63) >> 1;
  int boff1 = boff0 + 1024;
  int row1 = boff1 >> 6, ke1 = (boff1 & 63) >> 1;
  const short* ga0 = A + (size_t)(bm0 + row0) * 1024 + ke0;
  const short* ga1 = A + (size_t)(bm0 + row1) * 1024 + ke1;
  const short* gb0 = Bt + (size_t)(bn0 + row0) * 1024 + ke0;
  const short* gb1 = Bt + (size_t)(bn0 + row1) * 1024 + ke1;
  int lo = (w * 2) * 512, lo1 = (w * 2 + 1) * 512;

  for (int kb = 0; kb < 1024; kb += 64) {
    #pragma unroll
    for (int hh = 0; hh < 2; ++hh) {
      int kc = kb + hh * 32;
      GLD16(ga0 + kc, As[hh] + lo);
      GLD16(ga1 + kc, As[hh] + lo1);
      GLD16(gb0 + kc, Bs[hh] + lo);
      GLD16(gb1 + kc, Bs[hh] + lo1);
    }
    __syncthreads();
    #pragma unroll
    for (int hh = 0; hh < 2; ++hh) {
      short8 a[4], bfr[4];
      #pragma unroll
      for (int m = 0; m < 4; ++m)
        a[m] = *(const short8*)(As[hh] + (wr * 64 + m * 16 + lr) * 32 + lk * 8);
      #pragma unroll
      for (int n = 0; n < 4; ++n)
        bfr[n] = *(const short8*)(Bs[hh] + (wc * 64 + n * 16 + lr) * 32 + lk * 8);
      __builtin_amdgcn_s_setprio(1);
      #pragma unroll
      for (int m = 0; m < 4; ++m)
        #pragma unroll
        for (int n = 0; n < 4; ++n)
          acc[m][n] = __builtin_amdgcn_mfma_f32_16x16x32_bf16(a[m], bfr[n], acc[m][n], 0, 0, 0);
      __builtin_amdgcn_s_setprio(0);
    }
    __syncthreads();
  }
  #pragma unroll
  for (int m = 0; m < 4; ++m)
    #pragma unroll
    for (int n = 0; n < 4; ++n)
      #pragma unroll
      for (int i = 0; i < 4; ++i) {
        int r = bm0 + wr * 64 + m * 16 + lk * 4 + i;
        int cc = bn0 + wc * 64 + n * 16 + lr;
        C[(size_t)r * 1024 + cc] = f2bf(acc[m][n][i]);
      }
}

// ------------- kernel 4: V transpose  pv[b*N+n][h*64+dv] -> vt[hb][dv][n] -------------
__global__ __launch_bounds__(256) void vtrans(
    const short* __restrict__ pv, short* __restrict__ vt) {
  __shared__ short T[64 * 72];
  int t = threadIdx.x;
  int hb = blockIdx.y, h = hb >> 2, b = hb & 3;
  int n0 = blockIdx.x * 64;
  const short* src = pv + (size_t)b * 1048576 + (size_t)n0 * 1024 + h * 64;
  #pragma unroll
  for (int it = 0; it < 2; ++it) {
    int id = it * 256 + t;
    int row = id >> 3, seg = id & 7;
    *(short8*)(T + row * 72 + seg * 8) = *(const short8*)(src + (size_t)row * 1024 + seg * 8);
  }
  __syncthreads();
  short* dst = vt + (size_t)hb * 65536 + n0;
  #pragma unroll
  for (int it = 0; it < 2; ++it) {
    int id = it * 256 + t;
    int dv = id >> 3, seg = id & 7;
    short8 vv;
    #pragma unroll
    for (int jj = 0; jj < 8; ++jj) vv[jj] = T[(seg * 8 + jj) * 72 + dv];
    *(short8*)(dst + (size_t)dv * 1024 + seg * 8) = vv;
  }
}

// ------------- kernel 5: fused attention, SWAPPED QK^T (P lane-local along k) -------------
// mfma(K,Q): lane (lr,lk) holds S[q=lr][k=16n+4lk+i] -> softmax reduce = 2 shfl steps;
// P->Ps relay = 4x ds_write_b64 (was 16x b16); attn store direct from regs (no readback).
// K/V/Ps rows are 64 shorts with XOR swizzle (write pos8^(2*(lr&7)), read slot^(lr&7)).
__global__ __launch_bounds__(512) void attn_fused(
    const short* __restrict__ pq, const short* __restrict__ pk, const short* __restrict__ vt,
    float* __restrict__ dout) {
  __shared__ __attribute__((aligned(16))) short Ks[2][64 * 64];
  __shared__ __attribute__((aligned(16))) short Vs[2][64 * 64];
  __shared__ __attribute__((aligned(16))) short Ps[128 * 64];
  int t = threadIdx.x, l = t & 63, w = t >> 6;
  int lr = l & 15, lk = l >> 4;
  int r7 = lr & 7;
  int bid = blockIdx.x;
  int swz = (bid & 7) * 64 + (bid >> 3);           // XCD c -> hb in [c*8, c*8+8)
  int hb = swz >> 3, qt = swz & 7;
  int h = hb >> 2, b = hb & 3;                     // hb = h*B + b
  int q0 = qt * 128;
  const short* Qg = pq + (size_t)b * 1048576 + h * 64;
  const short* Kg = pk + (size_t)b * 1048576 + h * 64;
  const short* Vt = vt + (size_t)hb * 65536;
  float* attnp = dout + 4194304 + (size_t)hb * 1048576;
  const f32x4 Z = {0.f, 0.f, 0.f, 0.f};
  const float scale = 0.125f;
  int r0 = w * 16;
  int sj = t >> 3, slt = t & 7;                    // staging: row sj, slot slt
  int stoff = sj * 64 + ((slt ^ (sj & 7)) << 3);   // swizzled staging addr (shorts)

  // Q fragments direct from global (one-time)
  const short* qrow = Qg + (size_t)(q0 + r0 + lr) * 1024;
  short8 aq[2];
  aq[0] = *(const short8*)(qrow + lk * 8);
  aq[1] = *(const short8*)(qrow + 32 + lk * 8);

  short8 ka, va;
  // prologue: stage K chunk 0 -> buf 0
  ka = *(const short8*)(Kg + (size_t)sj * 1024 + slt * 8);
  *(short8*)(Ks[0] + stoff) = ka;
  BAR();

  float s = 0.0f;

  // ---- pass 1: sum of exp(scores); swapped mfma(K, Q) ----
  for (int nc = 0; nc < 16; ++nc) {
    int cur = nc & 1;
    if (nc < 15)
      ka = *(const short8*)(Kg + (size_t)((nc + 1) * 64 + sj) * 1024 + slt * 8);
    f32x4 acc[4] = {Z, Z, Z, Z};
    __builtin_amdgcn_s_setprio(1);
    #pragma unroll
    for (int kk = 0; kk < 2; ++kk)
      #pragma unroll
      for (int n = 0; n < 4; ++n) {
        short8 bk = *(const short8*)(Ks[cur] + (n * 16 + lr) * 64 + (((kk * 4 + lk) ^ r7) << 3));
        acc[n] = __builtin_amdgcn_mfma_f32_16x16x32_bf16(bk, aq[kk], acc[n], 0, 0, 0);
      }
    __builtin_amdgcn_s_setprio(0);
    #pragma unroll
    for (int n = 0; n < 4; ++n)
      s += __expf(acc[n][0] * scale) + __expf(acc[n][1] * scale) +
           __expf(acc[n][2] * scale) + __expf(acc[n][3] * scale);
    if (nc < 15)
      *(short8*)(Ks[cur ^ 1] + stoff) = ka;
    BAR();
  }
  // reduce across the 4 lk-groups sharing each q-row
  s += __shfl_xor(s, 16, 64);
  s += __shfl_xor(s, 32, 64);
  float inv = 1.0f / s;

  // re-prime buf 0 with chunk 0 (K and V)
  ka = *(const short8*)(Kg + (size_t)sj * 1024 + slt * 8);
  va = *(const short8*)(Vt + (size_t)sj * 1024 + slt * 8);
  *(short8*)(Ks[0] + stoff) = ka;
  *(short8*)(Vs[0] + stoff) = va;
  BAR();

  // ---- pass 2: swapped QK -> exp (lane-local) -> attn store from regs + Ps b64 -> PV ----
  f32x4 acco[4] = {Z, Z, Z, Z};
  float* arow = attnp + (size_t)(q0 + r0 + lr) * 1024 + lk * 4;
  short* psrow = Ps + (r0 + lr) * 64;
  int wsw = (lr & 7) << 1;                         // 8B-granular XOR key
  for (int nc = 0; nc < 16; ++nc) {
    int cur = nc & 1;
    if (nc < 15) {
      ka = *(const short8*)(Kg + (size_t)((nc + 1) * 64 + sj) * 1024 + slt * 8);
      va = *(const short8*)(Vt + (size_t)sj * 1024 + (nc + 1) * 64 + slt * 8);
    }
    f32x4 acc[4] = {Z, Z, Z, Z};
    __builtin_amdgcn_s_setprio(1);
    #pragma unroll
    for (int kk = 0; kk < 2; ++kk)
      #pragma unroll
      for (int n = 0; n < 4; ++n) {
        short8 bk = *(const short8*)(Ks[cur] + (n * 16 + lr) * 64 + (((kk * 4 + lk) ^ r7) << 3));
        acc[n] = __builtin_amdgcn_mfma_f32_16x16x32_bf16(bk, aq[kk], acc[n], 0, 0, 0);
      }
    __builtin_amdgcn_s_setprio(0);
    // normalized P: attn f32 direct from regs; bf16 4-pack -> Ps (b64, swizzled)
    #pragma unroll
    for (int n = 0; n < 4; ++n) {
      float e0 = __expf(acc[n][0] * scale) * inv;
      float e1 = __expf(acc[n][1] * scale) * inv;
      float e2 = __expf(acc[n][2] * scale) * inv;
      float e3 = __expf(acc[n][3] * scale) * inv;
      float4 fo = {e0, e1, e2, e3};
      *(float4*)(arow + nc * 64 + n * 16) = fo;    // col = nc*64 + 16n + 4lk + i
      short4_ p4;
      p4[0] = f2bf(e0); p4[1] = f2bf(e1); p4[2] = f2bf(e2); p4[3] = f2bf(e3);
      *(short4_*)(psrow + (((n * 4 + lk) ^ wsw) << 2)) = p4;
    }
    // PV: ap from Ps (b128, swizzled read matches b64 writes), bv from LDS V
    #pragma unroll
    for (int kk = 0; kk < 2; ++kk) {
      short8 ap = *(const short8*)(psrow + (((kk * 4 + lk) ^ r7) << 3));
      __builtin_amdgcn_s_setprio(1);
      #pragma unroll
      for (int f = 0; f < 4; ++f) {
        short8 bv = *(const short8*)(Vs[cur] + (f * 16 + lr) * 64 + (((kk * 4 + lk) ^ r7) << 3));
        acco[f] = __builtin_amdgcn_mfma_f32_16x16x32_bf16(ap, bv, acco[f], 0, 0, 0);
      }
      __builtin_amdgcn_s_setprio(0);
    }
    if (nc < 15) {
      *(short8*)(Ks[cur ^ 1] + stoff) = ka;
      *(short8*)(Vs[cur ^ 1] + stoff) = va;
    }
    BAR();
  }
  // out[b][n][h*64+dv] (f32); PV C-layout unchanged (col=dv, row=q)
  #pragma unroll
  for (int f = 0; f < 4; ++f)
    #pragma unroll
    for (int i = 0; i < 4; ++i) {
      int row = q0 + r0 + lk * 4 + i;
      int dv = f * 16 + lr;
      dout[(size_t)b * 1048576 + (size_t)row * 1024 + h * 64 + dv] = acco[f][i];
    }
}

extern "C" void kernel_launch(void* const* d_in, const int* in_sizes, int n_in,
                              void* d_out, int out_size, void* d_ws, size_t ws_size,
                              hipStream_t stream) {
  const void* big[3] = {0, 0, 0};
  const void* small[3] = {0, 0, 0};
  int nb = 0, ns = 0;
  for (int i = 0; i < n_in && i < 6; ++i) {
    if (in_sizes[i] == 4194304) { if (nb < 3) big[nb++] = d_in[i]; }
    else                        { if (ns < 3) small[ns++] = d_in[i]; }
  }
  const float *q, *k, *v, *wq, *wk, *wv;
  if (nb == 3 && ns == 3) {
    q = (const float*)big[0]; k = (const float*)big[1]; v = (const float*)big[2];
    wq = (const float*)small[0]; wk = (const float*)small[1]; wv = (const float*)small[2];
  } else {
    q = (const float*)d_in[0]; k = (const float*)d_in[1]; v = (const float*)d_in[2];
    wq = (const float*)d_in[3]; wk = (const float*)d_in[4]; wv = (const float*)d_in[5];
  }
  // workspace layout (shorts): total 32,505,856 shorts = 65 MB (validated size)
  short* W   = (short*)d_ws;
  short* xq  = W;
  short* xk  = W + 4194304;
  short* xv  = W + 8388608;
  short* wtq = W + 12582912;
  short* wtk = W + 13631488;
  short* wtv = W + 14680064;
  short* pq  = W + 15728640;
  short* pk  = W + 19922944;
  short* pv  = W + 24117248;
  short* vt  = W + 28311552;
  float* out = (float*)d_out;

  cast_pack<<<dim3(5120, 1, 3), 256, 0, stream>>>(q, k, v, wq, wk, wv,
                                                  xq, xk, xv, wtq, wtk, wtv);
  proj_gemm<<<dim3(8, 32, 3), 256, 0, stream>>>(xq, xk, xv, wtq, wtk, wtv, pq, pk, pv);
  vtrans<<<dim3(16, 64), 256, 0, stream>>>(pv, vt);
  attn_fused<<<dim3(512), 512, 0, stream>>>(pq, pk, vt, out);
}